// Round 2
// baseline (265.981 us; speedup 1.0000x reference)
//
#include <hip/hip_runtime.h>

#define D 128
#define MARGIN 1.0f
#define EPS 1e-6f
#define NB 2048            // blocks; 4 waves/block -> 8192 waves = 32/CU
#define WPB 4              // waves per block (blockDim = 256)

// One wave (64 lanes) per triple-pair: lanes 0-31 = pos triple, lanes 32-63 = neg.
// Each lane holds a float4 slice (l = lane&31) of every 128-float row.
// Final cross-block reduction fused via "last block reduces" (agent-scope atomics).
__global__ __launch_bounds__(256, 8) void transd_fused(
    const int* __restrict__ posX, const int* __restrict__ negX,
    const float* __restrict__ W_e, const float* __restrict__ W_ep,
    const float* __restrict__ W_r, const float* __restrict__ W_rp,
    float* __restrict__ partials, unsigned int* __restrict__ counter,
    float* __restrict__ out, int nTriples)
{
    const int tid  = threadIdx.x;
    const int wid  = tid >> 6;
    const int lane = tid & 63;
    const int l4   = (lane & 31) * 4;        // float offset of this lane's slice
    const int* __restrict__ X = (lane >= 32) ? negX : posX;

    const int gw = blockIdx.x * WPB + wid;   // global wave id
    const int nw = NB * WPB;                 // total waves

    // exact per-wave trip count (131072 / 8192 = 16, but stay generic)
    const int iters = (gw < nTriples) ? ((nTriples - 1 - gw) / nw + 1) : 0;

    float acc = 0.0f;

    // pipelined index registers
    int h = 0, r = 0, t = 0;
    if (iters > 0) {
        const int b0 = gw;
        h = X[b0 * 3 + 0]; r = X[b0 * 3 + 1]; t = X[b0 * 3 + 2];
    }

    for (int i = 0; i < iters; ++i) {
        // prefetch next iteration's indices (hides index->gather dependence)
        int nh = h, nr = r, nt = t;
        if (i + 1 < iters) {
            const int nb = gw + (i + 1) * nw;
            nh = X[nb * 3 + 0]; nr = X[nb * 3 + 1]; nt = X[nb * 3 + 2];
        }

        const size_t ho = (size_t)h * D + l4;
        const size_t to = (size_t)t * D + l4;
        const size_t ro = (size_t)r * D + l4;

        // 6 independent coalesced gathers (512 B per 32-lane half per row)
        const float4 head  = *(const float4*)(W_e  + ho);
        const float4 headp = *(const float4*)(W_ep + ho);
        const float4 tail  = *(const float4*)(W_e  + to);
        const float4 tailp = *(const float4*)(W_ep + to);
        const float4 rel   = *(const float4*)(W_r  + ro);
        const float4 relp  = *(const float4*)(W_rp + ro);

        float dh = headp.x * head.x + headp.y * head.y + headp.z * head.z + headp.w * head.w;
        float dt = tailp.x * tail.x + tailp.y * tail.y + tailp.z * tail.z + tailp.w * tail.w;

        // joint 32-lane butterfly (masks <32 never cross the pos/neg halves)
        #pragma unroll
        for (int m = 1; m <= 16; m <<= 1) {
            dh += __shfl_xor(dh, m, 64);
            dt += __shfl_xor(dt, m, 64);
        }
        const float dd = dh - dt;

        // diff = head - tail + rel + relp*(dh - dt) + EPS
        float4 diff;
        diff.x = fmaf(relp.x, dd, head.x - tail.x + rel.x + EPS);
        diff.y = fmaf(relp.y, dd, head.y - tail.y + rel.y + EPS);
        diff.z = fmaf(relp.z, dd, head.z - tail.z + rel.z + EPS);
        diff.w = fmaf(relp.w, dd, head.w - tail.w + rel.w + EPS);

        float ss = diff.x * diff.x + diff.y * diff.y + diff.z * diff.z + diff.w * diff.w;
        #pragma unroll
        for (int m = 1; m <= 16; m <<= 1) ss += __shfl_xor(ss, m, 64);

        const float score = sqrtf(ss);                 // lanes 0-31: pos, 32-63: neg
        const float other = __shfl_xor(score, 32, 64); // swap halves

        if (lane == 0) acc += fmaxf(0.0f, score - other + MARGIN);

        h = nh; r = nr; t = nt;
    }

    // ---- block partial ----
    __shared__ float sacc[WPB];
    __shared__ int   isLast;
    if (lane == 0) sacc[wid] = acc;
    __syncthreads();

    if (tid == 0) {
        float s = 0.0f;
        #pragma unroll
        for (int i = 0; i < WPB; ++i) s += sacc[i];
        __hip_atomic_store(&partials[blockIdx.x], s,
                           __ATOMIC_RELEASE, __HIP_MEMORY_SCOPE_AGENT);
        unsigned int old = __hip_atomic_fetch_add(counter, 1u,
                           __ATOMIC_ACQ_REL, __HIP_MEMORY_SCOPE_AGENT);
        isLast = (old == (unsigned)(NB - 1));
    }
    __syncthreads();

    // ---- last block performs the deterministic final reduction ----
    if (isLast) {
        __shared__ float red[256];
        float v = 0.0f;
        for (int i = tid; i < NB; i += 256)
            v += __hip_atomic_load(&partials[i],
                                   __ATOMIC_RELAXED, __HIP_MEMORY_SCOPE_AGENT);
        red[tid] = v;
        __syncthreads();
        #pragma unroll
        for (int k = 128; k > 0; k >>= 1) {
            if (tid < k) red[tid] += red[tid + k];
            __syncthreads();
        }
        if (tid == 0) out[0] = red[0] / (float)nTriples;
    }
}

extern "C" void kernel_launch(void* const* d_in, const int* in_sizes, int n_in,
                              void* d_out, int out_size, void* d_ws, size_t ws_size,
                              hipStream_t stream) {
    const int*   posX = (const int*)d_in[0];
    const int*   negX = (const int*)d_in[1];
    const float* W_e  = (const float*)d_in[2];
    const float* W_ep = (const float*)d_in[3];
    const float* W_r  = (const float*)d_in[4];
    const float* W_rp = (const float*)d_in[5];
    float* out = (float*)d_out;

    const int nTriples = in_sizes[0] / 3;   // 131072

    float*        partials = (float*)d_ws;
    unsigned int* counter  = (unsigned int*)((char*)d_ws + NB * sizeof(float));

    // reset the arrival counter each call (graph-capture safe, deterministic)
    hipMemsetAsync(counter, 0, sizeof(unsigned int), stream);

    hipLaunchKernelGGL(transd_fused, dim3(NB), dim3(256), 0, stream,
                       posX, negX, W_e, W_ep, W_r, W_rp,
                       partials, counter, out, nTriples);
}

// Round 3
// 97.726 us; speedup vs baseline: 2.7217x; 2.7217x over previous
//
#include <hip/hip_runtime.h>

#define D 128
#define MARGIN 1.0f
#define EPS 1e-6f
#define NB 2048            // 2048 blocks x 4 waves = 8192 waves = 32/CU (100% occ)
#define WPB 4

// One wave (64 lanes) per triple-pair: lanes 0-31 = pos triple, lanes 32-63 = neg.
// Each lane holds a float4 slice (l = lane&31) of every 128-float row.
// Tail: one plain (relaxed, device-scope) atomicAdd per block — NO acquire/release
// cache ops (round-2 lesson: agent-scope ACQ_REL flushed L2 2048x -> 3.3x slowdown).
__global__ __launch_bounds__(256, 8) void transd_main(
    const int* __restrict__ posX, const int* __restrict__ negX,
    const float* __restrict__ W_e, const float* __restrict__ W_ep,
    const float* __restrict__ W_r, const float* __restrict__ W_rp,
    float* __restrict__ out, int nTriples)
{
    const int tid  = threadIdx.x;
    const int wid  = tid >> 6;
    const int lane = tid & 63;
    const int l4   = (lane & 31) * 4;
    const int* __restrict__ X = (lane >= 32) ? negX : posX;

    const int gw = blockIdx.x * WPB + wid;
    const int nw = NB * WPB;

    float acc = 0.0f;

    for (int b = gw; b < nTriples; b += nw) {
        const int h = X[b * 3 + 0];
        const int r = X[b * 3 + 1];
        const int t = X[b * 3 + 2];

        const size_t ho = (size_t)h * D + l4;
        const size_t to = (size_t)t * D + l4;
        const size_t ro = (size_t)r * D + l4;

        // 6 independent coalesced gathers (512 B per 32-lane half per row)
        const float4 head  = *(const float4*)(W_e  + ho);
        const float4 headp = *(const float4*)(W_ep + ho);
        const float4 tail  = *(const float4*)(W_e  + to);
        const float4 tailp = *(const float4*)(W_ep + to);
        const float4 rel   = *(const float4*)(W_r  + ro);
        const float4 relp  = *(const float4*)(W_rp + ro);

        float dh = headp.x * head.x + headp.y * head.y + headp.z * head.z + headp.w * head.w;
        float dt = tailp.x * tail.x + tailp.y * tail.y + tailp.z * tail.z + tailp.w * tail.w;

        // joint 32-lane butterfly (masks <32 never cross the pos/neg halves)
        #pragma unroll
        for (int m = 1; m <= 16; m <<= 1) {
            dh += __shfl_xor(dh, m, 64);
            dt += __shfl_xor(dt, m, 64);
        }
        const float dd = dh - dt;

        // diff = head - tail + rel + relp*(dh - dt) + EPS
        float4 diff;
        diff.x = fmaf(relp.x, dd, head.x - tail.x + rel.x + EPS);
        diff.y = fmaf(relp.y, dd, head.y - tail.y + rel.y + EPS);
        diff.z = fmaf(relp.z, dd, head.z - tail.z + rel.z + EPS);
        diff.w = fmaf(relp.w, dd, head.w - tail.w + rel.w + EPS);

        float ss = diff.x * diff.x + diff.y * diff.y + diff.z * diff.z + diff.w * diff.w;
        #pragma unroll
        for (int m = 1; m <= 16; m <<= 1) ss += __shfl_xor(ss, m, 64);

        const float score = sqrtf(ss);                 // lanes 0-31: pos, 32-63: neg
        const float other = __shfl_xor(score, 32, 64); // swap halves

        if (lane == 0) acc += fmaxf(0.0f, score - other + MARGIN);
    }

    __shared__ float sacc[WPB];
    if (lane == 0) sacc[wid] = acc;
    __syncthreads();
    if (tid == 0) {
        float s = 0.0f;
        #pragma unroll
        for (int i = 0; i < WPB; ++i) s += sacc[i];
        atomicAdd(out, s / (float)nTriples);   // plain relaxed device-scope atomic
    }
}

extern "C" void kernel_launch(void* const* d_in, const int* in_sizes, int n_in,
                              void* d_out, int out_size, void* d_ws, size_t ws_size,
                              hipStream_t stream) {
    const int*   posX = (const int*)d_in[0];
    const int*   negX = (const int*)d_in[1];
    const float* W_e  = (const float*)d_in[2];
    const float* W_ep = (const float*)d_in[3];
    const float* W_r  = (const float*)d_in[4];
    const float* W_rp = (const float*)d_in[5];
    float* out = (float*)d_out;

    const int nTriples = in_sizes[0] / 3;   // 131072

    hipMemsetAsync(out, 0, sizeof(float), stream);  // graph-captured re-zero
    hipLaunchKernelGGL(transd_main, dim3(NB), dim3(256), 0, stream,
                       posX, negX, W_e, W_ep, W_r, W_rp, out, nTriples);
}

// Round 4
// 95.584 us; speedup vs baseline: 2.7827x; 1.0224x over previous
//
#include <hip/hip_runtime.h>

#define D 128
#define MARGIN 1.0f
#define EPS 1e-6f
#define NB 2048            // 2048 blocks x 4 waves = 8192 waves = 32/CU
#define WPB 4

// One wave (64 lanes) per triple-pair: lanes 0-31 = pos triple, lanes 32-63 = neg.
// Each lane holds a float4 slice (l = lane&31) of every 128-float row.
// v4: single dd-butterfly (11 cross-lane ops/iter instead of 16) + index prefetch.
__global__ __launch_bounds__(256, 8) void transd_main(
    const int* __restrict__ posX, const int* __restrict__ negX,
    const float* __restrict__ W_e, const float* __restrict__ W_ep,
    const float* __restrict__ W_r, const float* __restrict__ W_rp,
    float* __restrict__ partials, int nTriples)
{
    const int tid  = threadIdx.x;
    const int wid  = tid >> 6;
    const int lane = tid & 63;
    const int l4   = (lane & 31) * 4;
    const int* __restrict__ X = (lane >= 32) ? negX : posX;

    const int gw = blockIdx.x * WPB + wid;
    const int nw = NB * WPB;

    const int iters = (gw < nTriples) ? ((nTriples - 1 - gw) / nw + 1) : 0;

    float acc = 0.0f;

    // software-pipelined index registers (hide index->gather dependence)
    int h = 0, r = 0, t = 0;
    if (iters > 0) {
        h = X[gw * 3 + 0]; r = X[gw * 3 + 1]; t = X[gw * 3 + 2];
    }

    for (int i = 0; i < iters; ++i) {
        const size_t ho = (size_t)h * D + l4;
        const size_t to = (size_t)t * D + l4;
        const size_t ro = (size_t)r * D + l4;

        // issue next iteration's index loads before the gathers consume h/r/t
        int nh = h, nr = r, nt = t;
        if (i + 1 < iters) {
            const int nb = gw + (i + 1) * nw;
            nh = X[nb * 3 + 0]; nr = X[nb * 3 + 1]; nt = X[nb * 3 + 2];
        }

        // 6 independent coalesced gathers (512 B per 32-lane half per row)
        const float4 head  = *(const float4*)(W_e  + ho);
        const float4 headp = *(const float4*)(W_ep + ho);
        const float4 tail  = *(const float4*)(W_e  + to);
        const float4 tailp = *(const float4*)(W_ep + to);
        const float4 rel   = *(const float4*)(W_r  + ro);
        const float4 relp  = *(const float4*)(W_rp + ro);

        // we only ever need dd = sum(headp*head) - sum(tailp*tail):
        // reduce the per-lane DIFFERENCE with a single butterfly.
        float dpart = headp.x * head.x + headp.y * head.y
                    + headp.z * head.z + headp.w * head.w
                    - tailp.x * tail.x - tailp.y * tail.y
                    - tailp.z * tail.z - tailp.w * tail.w;
        #pragma unroll
        for (int m = 1; m <= 16; m <<= 1) dpart += __shfl_xor(dpart, m, 64);
        const float dd = dpart;

        // diff = head - tail + rel + relp*dd + EPS
        float4 diff;
        diff.x = fmaf(relp.x, dd, head.x - tail.x + rel.x + EPS);
        diff.y = fmaf(relp.y, dd, head.y - tail.y + rel.y + EPS);
        diff.z = fmaf(relp.z, dd, head.z - tail.z + rel.z + EPS);
        diff.w = fmaf(relp.w, dd, head.w - tail.w + rel.w + EPS);

        float ss = diff.x * diff.x + diff.y * diff.y + diff.z * diff.z + diff.w * diff.w;
        #pragma unroll
        for (int m = 1; m <= 16; m <<= 1) ss += __shfl_xor(ss, m, 64);

        const float score = sqrtf(ss);                 // lanes 0-31: pos, 32-63: neg
        const float other = __shfl_xor(score, 32, 64); // swap halves

        if (lane == 0) acc += fmaxf(0.0f, score - other + MARGIN);

        h = nh; r = nr; t = nt;
    }

    __shared__ float sacc[WPB];
    if (lane == 0) sacc[wid] = acc;
    __syncthreads();
    if (tid == 0) {
        float s = 0.0f;
        #pragma unroll
        for (int i = 0; i < WPB; ++i) s += sacc[i];
        partials[blockIdx.x] = s;
    }
}

__global__ void transd_reduce(const float* __restrict__ partial, int n,
                              float* __restrict__ out, int nTriples)
{
    __shared__ float s[256];
    float v = 0.0f;
    for (int i = threadIdx.x; i < n; i += 256) v += partial[i];
    s[threadIdx.x] = v;
    __syncthreads();
    for (int k = 128; k > 0; k >>= 1) {
        if ((int)threadIdx.x < k) s[threadIdx.x] += s[threadIdx.x + k];
        __syncthreads();
    }
    if (threadIdx.x == 0) out[0] = s[0] / (float)nTriples;
}

extern "C" void kernel_launch(void* const* d_in, const int* in_sizes, int n_in,
                              void* d_out, int out_size, void* d_ws, size_t ws_size,
                              hipStream_t stream) {
    const int*   posX = (const int*)d_in[0];
    const int*   negX = (const int*)d_in[1];
    const float* W_e  = (const float*)d_in[2];
    const float* W_ep = (const float*)d_in[3];
    const float* W_r  = (const float*)d_in[4];
    const float* W_rp = (const float*)d_in[5];
    float* out = (float*)d_out;

    const int nTriples = in_sizes[0] / 3;   // 131072

    float* partials = (float*)d_ws;         // NB floats (8 KB) of scratch
    hipLaunchKernelGGL(transd_main, dim3(NB), dim3(256), 0, stream,
                       posX, negX, W_e, W_ep, W_r, W_rp, partials, nTriples);
    hipLaunchKernelGGL(transd_reduce, dim3(1), dim3(256), 0, stream,
                       partials, NB, out, nTriples);
}